// Round 10
// baseline (511.705 us; speedup 1.0000x reference)
//
#include <hip/hip_runtime.h>
#include <stdint.h>

#define NN 8000            // nodes
#define UU 64              // units
#define EE 64000           // edges per support
#define BB 32              // batch
#define NB 256000          // NN*BB rows of the logical GEMM
#define HXS 512000         // NN*UU (per-batch stride in hx)

typedef __attribute__((ext_vector_type(8))) __bf16 bf16x8;
typedef __attribute__((ext_vector_type(4))) float f32x4;
typedef __attribute__((ext_vector_type(4))) unsigned int u32x4;

__device__ __forceinline__ unsigned short f2bf(float f){
  unsigned int u = __builtin_bit_cast(unsigned int, f);
  u += 0x7fffu + ((u >> 16) & 1u);
  return (unsigned short)(u >> 16);
}
__device__ __forceinline__ unsigned int pack2(float a, float b){
  return (unsigned int)f2bf(a) | ((unsigned int)f2bf(b) << 16);
}
__device__ __forceinline__ float bflo(unsigned int w){ return __builtin_bit_cast(float, w << 16); }
__device__ __forceinline__ float bfhi(unsigned int w){ return __builtin_bit_cast(float, w & 0xffff0000u); }
__device__ __forceinline__ float bfu(unsigned short v){ return __builtin_bit_cast(float, (unsigned int)v << 16); }

__device__ __forceinline__ void acc8(float* a, float v, uint4 q){
  a[0]+=v*bflo(q.x); a[1]+=v*bfhi(q.x); a[2]+=v*bflo(q.y); a[3]+=v*bfhi(q.y);
  a[4]+=v*bflo(q.z); a[5]+=v*bfhi(q.z); a[6]+=v*bflo(q.w); a[7]+=v*bfhi(q.w);
}

// async global->LDS, 16B per lane; LDS dest = wave-uniform base + lane*16 (linear).
__device__ __forceinline__ void stage16(const unsigned short* g, unsigned short* ldsbase){
  __builtin_amdgcn_global_load_lds((const __attribute__((address_space(1))) void*)g,
                                   (__attribute__((address_space(3))) void*)ldsbase, 16, 0, 0);
}

__device__ __forceinline__ void ntstore16(uint4 v, uint4* p){
  u32x4 ov = {v.x, v.y, v.z, v.w};
  __builtin_nontemporal_store(ov, (u32x4*)p);
}

// ---------------- CSR build ----------------
__global__ void k_hist(const int* __restrict__ r0, const int* __restrict__ r1, int* __restrict__ cnt){
  int i = blockIdx.x * 256 + threadIdx.x;
  if (i < 2*EE){
    int s = (i >= EE);
    int r = s ? r1[i - EE] : r0[i];
    atomicAdd(&cnt[s*NN + r], 1);
  }
}

__global__ __launch_bounds__(1024) void k_scan(const int* __restrict__ cnt, int* __restrict__ row_ptr, int* __restrict__ rp_work){
  int sup = blockIdx.x;
  const int* c = cnt + sup*NN;
  __shared__ int part[1024];
  int t = threadIdx.x;
  int loc[8]; int s = 0;
  #pragma unroll
  for (int j=0;j<8;j++){ int idx=t*8+j; int v = (idx<NN)? c[idx]:0; loc[j]=s; s+=v; }
  part[t]=s; __syncthreads();
  for (int o=1;o<1024;o<<=1){
    int v = (t>=o)? part[t-o]:0;
    __syncthreads();
    part[t]+=v;
    __syncthreads();
  }
  int pre = (t>0)? part[t-1]:0;
  #pragma unroll
  for (int j=0;j<8;j++){ int idx=t*8+j; if(idx<NN){ int e=pre+loc[j]; row_ptr[sup*(NN+1)+idx]=e; rp_work[sup*NN+idx]=e; } }
  if (t==1023) row_ptr[sup*(NN+1)+NN] = part[1023];
}

__global__ void k_scatter(const int* __restrict__ r0, const int* __restrict__ c0, const float* __restrict__ v0,
                          const int* __restrict__ r1, const int* __restrict__ c1, const float* __restrict__ v1,
                          int* __restrict__ rp_work, uint2* __restrict__ edge_s){
  int i = blockIdx.x * 256 + threadIdx.x;
  if (i < 2*EE){
    int s = (i >= EE);
    int e = s ? i - EE : i;
    int r  = s ? r1[e] : r0[e];
    int cc = s ? c1[e] : c0[e];
    float vv = s ? v1[e] : v0[e];
    int pos = atomicAdd(&rp_work[s*NN + r], 1);
    uint2 ev; ev.x = (unsigned int)cc; ev.y = __builtin_bit_cast(unsigned int, vv);
    edge_s[s*EE + pos] = ev;
  }
}

// ---------------- weight repack (Chebyshev absorbed, column-permuted) ----------------
// GEMM col c -> output unit o = 4*(c&15) + ((c>>4)&3); r/u block kept by c<64.
// Wp layout: m 0..4: [m][NCOL][64k] ; tail at 320*NCOL: [NCOL][32k]
__global__ void k_wpack(const float* __restrict__ W_ru, const float* __restrict__ W_c,
                        unsigned short* __restrict__ Wru_t, unsigned short* __restrict__ Wc_t){
  int i = blockIdx.x * 256 + threadIdx.x;   // 352*192 total
  int k = i / 192; int oo = i % 192;
  const float* W; int ld, NC; unsigned short* dst; int c;
  if (oo < 128){ W = W_ru; ld = 128; NC = 128; dst = Wru_t; c = oo; }
  else         { W = W_c;  ld = 64;  NC = 64;  dst = Wc_t;  c = oo - 128; }
  int o = 4*(c & 15) + ((c >> 4) & 3);
  int wcol = (c >= 64) ? 64 + o : o;
  float v = 0.f;
  if (k < 330){
    int m, fb;
    if (k < 320){ m = k >> 6; fb = (2 + (k & 63)) * 5; }
    else        { int j = k - 320; m = j >> 1; fb = (j & 1) * 5; }
    if      (m==0) v = W[(fb+0)*ld+wcol] - W[(fb+2)*ld+wcol] - W[(fb+4)*ld+wcol];
    else if (m==1) v = W[(fb+1)*ld+wcol];
    else if (m==2) v = 2.f*W[(fb+2)*ld+wcol];
    else if (m==3) v = W[(fb+3)*ld+wcol];
    else           v = 2.f*W[(fb+4)*ld+wcol];
  }
  int dstoff;
  if (k < 320) dstoff = (k>>6)*NC*64 + c*64 + (k&63);
  else         dstoff = 320*NC + c*32 + (k-320);
  dst[dstoff] = f2bf(v);
}

// ---------------- build x0 ----------------
// state slab per m: row-major [n*32+b][64u] bf16 (4KB per node)
// xi slab per m: [8 s][NN] uint4 (4 bins of dword)
__global__ void k_x0(const float* __restrict__ inputs, const float* __restrict__ hx,
                     uint4* __restrict__ xs0q, unsigned int* __restrict__ xi0){
  int n = blockIdx.x, t = threadIdx.x;
  int b = t >> 3, ug = t & 7;
  const float4 h0 = *(const float4*)(hx + (size_t)b*HXS + n*64 + ug*8);
  const float4 h1 = *(const float4*)(hx + (size_t)b*HXS + n*64 + ug*8 + 4);
  uint4 o;
  o.x = pack2(h0.x, h0.y); o.y = pack2(h0.z, h0.w);
  o.z = pack2(h1.x, h1.y); o.w = pack2(h1.z, h1.w);
  xs0q[((size_t)n*32 + b)*8 + ug] = o;
  if (t < 32){
    int bb = t;
    const float2 g = *(const float2*)(inputs + (size_t)bb*(NN*2) + n*2);
    xi0[(((size_t)(bb>>2)*NN) + n)*4 + (bb&3)] = pack2(g.x, g.y);
  }
}

// ---------------- SpMM: one wave per (node, support); scalar edge meta ----------------
// state: 4000 blocks x 4 waves = 16000 waves = 2 sup x 8000 nodes.
// Each wave owns the full 4KB dst row; lane covers 4 x 16B chunks (stride 1KB).
// Edge list is wave-uniform -> meta via s_load, gathers via sgpr-base + fixed voffset.
template<bool WITH_IN>
__global__ __launch_bounds__(256) void k_spmm(const int* __restrict__ row_ptr, const uint2* __restrict__ edge_s,
                                              unsigned short* xsS, uint4* xi4,
                                              int srcA, int dstA, int srcB, int dstB){
  int bid = blockIdx.x;
  if (WITH_IN && bid >= 4000){
    int b2 = bid - 4000;
    int s = b2 & 7, supi = (b2 >> 3) & 1, chunk = b2 >> 4;
    int n = chunk*256 + threadIdx.x;
    if (n >= NN) return;
    int msrc = supi ? srcB : srcA, mdst = supi ? dstB : dstA;
    size_t sb = (size_t)(msrc*8 + s)*NN, db = (size_t)(mdst*8 + s)*NN;
    int beg = row_ptr[supi*(NN+1)+n], end = row_ptr[supi*(NN+1)+n+1];
    const uint2* es = edge_s + supi*EE;
    float ai[8] = {0.f,0.f,0.f,0.f,0.f,0.f,0.f,0.f};
    for (int e = beg; e < end; ++e){
      uint2 ev = es[e];
      float v = __builtin_bit_cast(float, ev.y);
      uint4 qi = xi4[sb + ev.x];
      acc8(ai, v, qi);
    }
    uint4 oi;
    oi.x = pack2(ai[0],ai[1]); oi.y = pack2(ai[2],ai[3]); oi.z = pack2(ai[4],ai[5]); oi.w = pack2(ai[6],ai[7]);
    if (supi) ntstore16(oi, &xi4[db + n]); else xi4[db + n] = oi;
    return;
  }
  int w = bid*4 + (threadIdx.x >> 6);
  w = __builtin_amdgcn_readfirstlane(w);
  int supi = (w >= NN) ? 1 : 0;
  int n = w - supi*NN;
  int lane = threadIdx.x & 63;
  int lo = lane*8;                         // shorts: lane's first 16B chunk
  int msrc = supi ? srcB : srcA, mdst = supi ? dstB : dstA;
  const unsigned short* srcS = xsS + (size_t)msrc*(NN*2048);
  unsigned short* dstS = xsS + (size_t)mdst*(NN*2048);
  int beg = __builtin_amdgcn_readfirstlane(row_ptr[supi*(NN+1)+n]);
  int end = __builtin_amdgcn_readfirstlane(row_ptr[supi*(NN+1)+n+1]);
  const uint2* es = edge_s + supi*EE;

  float a[32];
  #pragma unroll
  for (int i=0;i<32;i++) a[i] = 0.f;

  uint4 qc[4]; float vc = 0.f;
  if (beg < end){
    uint2 ev = es[beg];
    vc = __builtin_bit_cast(float, ev.y);
    const unsigned short* rp = srcS + (size_t)ev.x*2048;
    #pragma unroll
    for (int c=0;c<4;c++) qc[c] = *(const uint4*)(rp + lo + c*512);
  }
  for (int e = beg; e < end; ++e){
    uint4 qn[4]; float vn = 0.f;
    if (e+1 < end){
      uint2 ev = es[e+1];
      vn = __builtin_bit_cast(float, ev.y);
      const unsigned short* rp = srcS + (size_t)ev.x*2048;
      #pragma unroll
      for (int c=0;c<4;c++) qn[c] = *(const uint4*)(rp + lo + c*512);
    }
    #pragma unroll
    for (int c=0;c<4;c++) acc8(a + c*8, vc, qc[c]);
    #pragma unroll
    for (int c=0;c<4;c++) qc[c] = qn[c];
    vc = vn;
  }
  #pragma unroll
  for (int c=0;c<4;c++){
    uint4 o;
    o.x = pack2(a[c*8+0],a[c*8+1]); o.y = pack2(a[c*8+2],a[c*8+3]);
    o.z = pack2(a[c*8+4],a[c*8+5]); o.w = pack2(a[c*8+6],a[c*8+7]);
    ntstore16(o, (uint4*)(dstS + (size_t)n*2048 + lo + c*512));
  }
}

// ---------------- GEMM (R7 structure): 4 independent 32-row waves, A global->reg dbuf, B small LDS dbuf ----------------
template<int NCOL, bool IS_RU>
__global__ __launch_bounds__(256, 3) void k_gemm(unsigned short* xsS,                   // state slabs (slab0 = hx-bf16 / r*hx target)
                                                 const unsigned int* __restrict__ xsI,  // input dwords (8-slice layout)
                                                 const unsigned short* __restrict__ Wp, // packed [m][NCOL][64] + tail [NCOL][32]
                                                 const float* __restrict__ bias,
                                                 const float* __restrict__ hx,
                                                 float* cout,
                                                 unsigned short* ubuf){
  constexpr int CF = NCOL / 16;
  __shared__ unsigned short Bl[2][NCOL*64];
  __shared__ unsigned short Bt[NCOL*32];
  const int t = threadIdx.x;
  const int wv = t >> 6;
  const int l = t & 63;
  const int lr = l & 15;
  const int lg = l >> 4;
  const int R0 = blockIdx.x * 128;

  auto stageB = [&](int m, int buf){
    #pragma unroll
    for (int i=0;i<NCOL*8/256;i++){
      int g = t + i*256;
      int rr = g >> 3, c = g & 7;
      const unsigned short* gp = Wp + (size_t)(m*NCOL + rr)*64 + ((c ^ (rr&7)) << 3);
      stage16(gp, &Bl[buf][(size_t)(i*256 + wv*64)*8]);
    }
  };

  // per-wave A row bases (shorts; layout row-major [gemm_row][64])
  size_t abase[2];
  #pragma unroll
  for (int rf=0; rf<2; rf++)
    abase[rf] = (size_t)(R0 + wv*32 + rf*16 + lr)*64;
  auto loadA = [&](int m, uint4* dst){
    #pragma unroll
    for (int ks=0; ks<2; ks++)
      #pragma unroll
      for (int rf=0; rf<2; rf++)
        dst[ks*2+rf] = *(const uint4*)(xsS + (size_t)m*(NN*2048) + abase[rf] + ks*32 + lg*8);
  };

  // ---- prologue: A(m=0), tail frags, B0 + Btail ----
  uint4 aC[4], aN[4];
  loadA(0, aC);
  uint4 aT[2];
  #pragma unroll
  for (int rf=0; rf<2; rf++){
    int row = R0 + wv*32 + rf*16 + lr;
    int n = row >> 5, b = row & 31;
    size_t ib = (((size_t)(b>>2))*NN + n)*4 + (b&3);
    unsigned int q0=0u,q1=0u,q2=0u,q3=0u;
    if (lg == 0){
      q0 = xsI[ib];
      q1 = xsI[(size_t)8*NN*4 + ib];
      q2 = xsI[(size_t)16*NN*4 + ib];
      q3 = xsI[(size_t)24*NN*4 + ib];
    } else if (lg == 1){
      q0 = xsI[(size_t)32*NN*4 + ib];
    }
    uint4 qq; qq.x=q0; qq.y=q1; qq.z=q2; qq.w=q3;
    aT[rf] = qq;
  }
  stageB(0, 0);
  {
    #pragma unroll
    for (int i=0;i<NCOL*4/256;i++){
      int g = t + i*256;
      int rr = g >> 2, c = g & 3;
      const unsigned short* gp = Wp + (size_t)320*NCOL + rr*32 + ((c ^ (rr&3)) << 3);
      stage16(gp, &Bt[(size_t)(i*256 + wv*64)*8]);
    }
  }
  __syncthreads();

  f32x4 acc[2][CF];
  const f32x4 zero = {0.f,0.f,0.f,0.f};
  #pragma unroll
  for (int rf=0; rf<2; rf++)
    #pragma unroll
    for (int cf=0; cf<CF; cf++) acc[rf][cf] = zero;

  #pragma unroll
  for (int m=0; m<5; m++){
    int cur = m & 1;
    if (m < 4){
      stageB(m+1, cur^1);
      loadA(m+1, aN);
    }
    #pragma unroll
    for (int ks=0; ks<2; ks++){
      #pragma unroll
      for (int cf=0; cf<CF; cf++){
        int col = cf*16 + lr;
        int chunk = (ks*4 + lg) ^ (col & 7);
        bf16x8 bv = __builtin_bit_cast(bf16x8, *(const uint4*)(&Bl[cur][col*64 + chunk*8]));
        acc[0][cf] = __builtin_amdgcn_mfma_f32_16x16x32_bf16(__builtin_bit_cast(bf16x8, aC[ks*2+0]), bv, acc[0][cf], 0, 0, 0);
        acc[1][cf] = __builtin_amdgcn_mfma_f32_16x16x32_bf16(__builtin_bit_cast(bf16x8, aC[ks*2+1]), bv, acc[1][cf], 0, 0, 0);
      }
    }
    __syncthreads();
    #pragma unroll
    for (int i=0;i<4;i++) aC[i] = aN[i];
  }

  // ---- tail K-step (input features) ----
  #pragma unroll
  for (int cf=0; cf<CF; cf++){
    int col = cf*16 + lr;
    int chunk = lg ^ (col & 3);
    bf16x8 bv = __builtin_bit_cast(bf16x8, *(const uint4*)(&Bt[col*32 + chunk*8]));
    acc[0][cf] = __builtin_amdgcn_mfma_f32_16x16x32_bf16(__builtin_bit_cast(bf16x8, aT[0]), bv, acc[0][cf], 0, 0, 0);
    acc[1][cf] = __builtin_amdgcn_mfma_f32_16x16x32_bf16(__builtin_bit_cast(bf16x8, aT[1]), bv, acc[1][cf], 0, 0, 0);
  }

  // ---- epilogue (col c -> unit 4*lr+cf; vectorized stores) ----
  #pragma unroll
  for (int rf=0; rf<2; rf++){
    #pragma unroll
    for (int reg=0; reg<4; reg++){
      int row = R0 + wv*32 + rf*16 + (lg << 2) + reg;
      int n = row >> 5, b = row & 31;
      size_t rowoff = (size_t)b*HXS + (size_t)n*UU;
      size_t slot0 = (size_t)row*64;
      int o0 = lr << 2;
      if constexpr (IS_RU){
        uint2 hv = *(const uint2*)(xsS + slot0 + o0);   // hx bf16 (slab0, pre-overwrite)
        unsigned short rr4[4], uu4[4];
        #pragma unroll
        for (int cf=0; cf<4; cf++){
          int o = o0 + cf;
          float vr = acc[rf][cf][reg]   + bias[o];
          float vu = acc[rf][cf+4][reg] + bias[64+o];
          float sgr = 1.f/(1.f + __expf(-vr));
          float sgu = 1.f/(1.f + __expf(-vu));
          float h = bfu(((const unsigned short*)&hv)[cf]);
          rr4[cf] = f2bf(sgr * h);
          uu4[cf] = f2bf(sgu);
        }
        *(uint2*)(xsS + slot0 + o0) = *(uint2*)rr4;
        *(uint2*)(ubuf + rowoff + o0) = *(uint2*)uu4;
      } else {
        float4 hv = *(const float4*)(hx + rowoff + o0);
        uint2 uv = *(const uint2*)(ubuf + rowoff + o0);
        float4 ov;
        #pragma unroll
        for (int cf=0; cf<4; cf++){
          float cc = tanhf(acc[rf][cf][reg] + bias[o0+cf]);
          float uu = bfu(((const unsigned short*)&uv)[cf]);
          float h  = ((const float*)&hv)[cf];
          ((float*)&ov)[cf] = uu*h + (1.f - uu)*cc;
        }
        *(float4*)(cout + rowoff + o0) = ov;
      }
    }
  }
}

// ---------------- launcher ----------------
extern "C" void kernel_launch(void* const* d_in, const int* in_sizes, int n_in,
                              void* d_out, int out_size, void* d_ws, size_t ws_size,
                              hipStream_t stream){
  const float* inputs = (const float*)d_in[0];
  const float* hx     = (const float*)d_in[1];
  const int*   row0   = (const int*)d_in[2];
  const int*   col0   = (const int*)d_in[3];
  const float* val0   = (const float*)d_in[4];
  const int*   row1   = (const int*)d_in[5];
  const int*   col1   = (const int*)d_in[6];
  const float* val1   = (const float*)d_in[7];
  const float* W_ru   = (const float*)d_in[8];
  const float* b_ru   = (const float*)d_in[9];
  const float* W_c    = (const float*)d_in[10];
  const float* b_c    = (const float*)d_in[11];
  float* out = (float*)d_out;

  char* ws = (char*)d_ws;
  size_t off = 0;
  auto alloc = [&](size_t bytes) -> void* {
    void* p = ws + off;
    off += (bytes + 255) & ~(size_t)255;
    return p;
  };
  unsigned short* xsS   = (unsigned short*)alloc((size_t)5*NN*2048*2);  // 163.84 MB
  unsigned int*   xsI   = (unsigned int*)  alloc((size_t)5*8*NN*16);    //   5.12 MB
  unsigned short* u_buf = (unsigned short*)alloc((size_t)NB*64*2);      //  32.77 MB
  unsigned short* Wru_t = (unsigned short*)alloc((size_t)128*352*2);
  unsigned short* Wc_t  = (unsigned short*)alloc((size_t)64*352*2);
  int*   row_ptr = (int*)  alloc(2*(NN+1)*4);
  uint2* edge_s  = (uint2*)alloc((size_t)2*EE*8);
  int*   cnt     = (int*)  alloc(2*NN*4);
  int*   rp_work = (int*)  alloc(2*NN*4);
  (void)ws_size; (void)in_sizes; (void)n_in; (void)out_size;

  hipMemsetAsync(cnt, 0, 2*NN*4, stream);
  k_hist<<<(2*EE + 255)/256, 256, 0, stream>>>(row0, row1, cnt);
  k_scan<<<2, 1024, 0, stream>>>(cnt, row_ptr, rp_work);
  k_scatter<<<(2*EE + 255)/256, 256, 0, stream>>>(row0, col0, val0, row1, col1, val1, rp_work, edge_s);
  k_wpack<<<(352*192)/256, 256, 0, stream>>>(W_ru, W_c, Wru_t, Wc_t);
  k_x0<<<NN, 256, 0, stream>>>(inputs, hx, (uint4*)xsS, (unsigned int*)xsI);

  uint4* xi4 = (uint4*)xsI;

  // gconv 1: hop1 (supports 0,1: m0->m1, m0->m3), hop2 (m1->m2, m3->m4); +512 input blocks each
  k_spmm<true ><<<4512, 256, 0, stream>>>(row_ptr, edge_s, xsS, xi4, 0, 1, 0, 3);
  k_spmm<true ><<<4512, 256, 0, stream>>>(row_ptr, edge_s, xsS, xi4, 1, 2, 3, 4);
  k_gemm<128, true><<<2000, 256, 0, stream>>>(xsS, xsI, Wru_t, b_ru, hx, nullptr, u_buf);

  // gconv 2: state part = r*hx (slab 0); input diffusion reused from gconv1
  k_spmm<false><<<4000, 256, 0, stream>>>(row_ptr, edge_s, xsS, xi4, 0, 1, 0, 3);
  k_spmm<false><<<4000, 256, 0, stream>>>(row_ptr, edge_s, xsS, xi4, 1, 2, 3, 4);
  k_gemm<64, false><<<2000, 256, 0, stream>>>(xsS, xsI, Wc_t, b_c, hx, out, u_buf);
}

// Round 11
// 451.200 us; speedup vs baseline: 1.1341x; 1.1341x over previous
//
#include <hip/hip_runtime.h>
#include <stdint.h>

#define NN 8000            // nodes
#define UU 64              // units
#define EE 64000           // edges per support
#define BB 32              // batch
#define NB 256000          // NN*BB rows of the logical GEMM
#define HXS 512000         // NN*UU (per-batch stride in hx)

typedef __attribute__((ext_vector_type(8))) __bf16 bf16x8;
typedef __attribute__((ext_vector_type(4))) float f32x4;
typedef __attribute__((ext_vector_type(4))) unsigned int u32x4;
typedef __attribute__((ext_vector_type(2))) unsigned int u32x2;

__device__ __forceinline__ unsigned short f2bf(float f){
  unsigned int u = __builtin_bit_cast(unsigned int, f);
  u += 0x7fffu + ((u >> 16) & 1u);
  return (unsigned short)(u >> 16);
}
__device__ __forceinline__ unsigned int pack2(float a, float b){
  return (unsigned int)f2bf(a) | ((unsigned int)f2bf(b) << 16);
}
__device__ __forceinline__ float bflo(unsigned int w){ return __builtin_bit_cast(float, w << 16); }
__device__ __forceinline__ float bfhi(unsigned int w){ return __builtin_bit_cast(float, w & 0xffff0000u); }
__device__ __forceinline__ float bfu(unsigned short v){ return __builtin_bit_cast(float, (unsigned int)v << 16); }

__device__ __forceinline__ void acc8(float* a, float v, uint4 q){
  a[0]+=v*bflo(q.x); a[1]+=v*bfhi(q.x); a[2]+=v*bflo(q.y); a[3]+=v*bfhi(q.y);
  a[4]+=v*bflo(q.z); a[5]+=v*bfhi(q.z); a[6]+=v*bflo(q.w); a[7]+=v*bfhi(q.w);
}

// async global->LDS, 16B per lane; LDS dest = wave-uniform base + lane*16 (linear).
__device__ __forceinline__ void stage16(const unsigned short* g, unsigned short* ldsbase){
  __builtin_amdgcn_global_load_lds((const __attribute__((address_space(1))) void*)g,
                                   (__attribute__((address_space(3))) void*)ldsbase, 16, 0, 0);
}

__device__ __forceinline__ void ntstore16(uint4 v, uint4* p){
  u32x4 ov = {v.x, v.y, v.z, v.w};
  __builtin_nontemporal_store(ov, (u32x4*)p);
}
__device__ __forceinline__ void ntstore8(uint2 v, uint2* p){
  u32x2 ov = {v.x, v.y};
  __builtin_nontemporal_store(ov, (u32x2*)p);
}

// ---------------- CSR build ----------------
__global__ void k_hist(const int* __restrict__ r0, const int* __restrict__ r1, int* __restrict__ cnt){
  int i = blockIdx.x * 256 + threadIdx.x;
  if (i < 2*EE){
    int s = (i >= EE);
    int r = s ? r1[i - EE] : r0[i];
    atomicAdd(&cnt[s*NN + r], 1);
  }
}

__global__ __launch_bounds__(1024) void k_scan(const int* __restrict__ cnt, int* __restrict__ row_ptr, int* __restrict__ rp_work){
  int sup = blockIdx.x;
  const int* c = cnt + sup*NN;
  __shared__ int part[1024];
  int t = threadIdx.x;
  int loc[8]; int s = 0;
  #pragma unroll
  for (int j=0;j<8;j++){ int idx=t*8+j; int v = (idx<NN)? c[idx]:0; loc[j]=s; s+=v; }
  part[t]=s; __syncthreads();
  for (int o=1;o<1024;o<<=1){
    int v = (t>=o)? part[t-o]:0;
    __syncthreads();
    part[t]+=v;
    __syncthreads();
  }
  int pre = (t>0)? part[t-1]:0;
  #pragma unroll
  for (int j=0;j<8;j++){ int idx=t*8+j; if(idx<NN){ int e=pre+loc[j]; row_ptr[sup*(NN+1)+idx]=e; rp_work[sup*NN+idx]=e; } }
  if (t==1023) row_ptr[sup*(NN+1)+NN] = part[1023];
}

__global__ void k_scatter(const int* __restrict__ r0, const int* __restrict__ c0, const float* __restrict__ v0,
                          const int* __restrict__ r1, const int* __restrict__ c1, const float* __restrict__ v1,
                          int* __restrict__ rp_work, uint2* __restrict__ edge_s){
  int i = blockIdx.x * 256 + threadIdx.x;
  if (i < 2*EE){
    int s = (i >= EE);
    int e = s ? i - EE : i;
    int r  = s ? r1[e] : r0[e];
    int cc = s ? c1[e] : c0[e];
    float vv = s ? v1[e] : v0[e];
    int pos = atomicAdd(&rp_work[s*NN + r], 1);
    uint2 ev; ev.x = (unsigned int)cc; ev.y = __builtin_bit_cast(unsigned int, vv);
    edge_s[s*EE + pos] = ev;
  }
}

// ---------------- weight repack (Chebyshev absorbed, column-permuted) ----------------
__global__ void k_wpack(const float* __restrict__ W_ru, const float* __restrict__ W_c,
                        unsigned short* __restrict__ Wru_t, unsigned short* __restrict__ Wc_t){
  int i = blockIdx.x * 256 + threadIdx.x;   // 352*192 total
  int k = i / 192; int oo = i % 192;
  const float* W; int ld, NC; unsigned short* dst; int c;
  if (oo < 128){ W = W_ru; ld = 128; NC = 128; dst = Wru_t; c = oo; }
  else         { W = W_c;  ld = 64;  NC = 64;  dst = Wc_t;  c = oo - 128; }
  int o = 4*(c & 15) + ((c >> 4) & 3);
  int wcol = (c >= 64) ? 64 + o : o;
  float v = 0.f;
  if (k < 330){
    int m, fb;
    if (k < 320){ m = k >> 6; fb = (2 + (k & 63)) * 5; }
    else        { int j = k - 320; m = j >> 1; fb = (j & 1) * 5; }
    if      (m==0) v = W[(fb+0)*ld+wcol] - W[(fb+2)*ld+wcol] - W[(fb+4)*ld+wcol];
    else if (m==1) v = W[(fb+1)*ld+wcol];
    else if (m==2) v = 2.f*W[(fb+2)*ld+wcol];
    else if (m==3) v = W[(fb+3)*ld+wcol];
    else           v = 2.f*W[(fb+4)*ld+wcol];
  }
  int dstoff;
  if (k < 320) dstoff = (k>>6)*NC*64 + c*64 + (k&63);
  else         dstoff = 320*NC + c*32 + (k-320);
  dst[dstoff] = f2bf(v);
}

// ---------------- build x0 ----------------
// state slab per m: row-major [n*32+b][64u] bf16 (4KB per node)
// xi slab per m: [8 s][NN] uint4 (4 bins of dword)
__global__ void k_x0(const float* __restrict__ inputs, const float* __restrict__ hx,
                     uint4* __restrict__ xs0q, unsigned int* __restrict__ xi0){
  int n = blockIdx.x, t = threadIdx.x;
  int b = t >> 3, ug = t & 7;
  const float4 h0 = *(const float4*)(hx + (size_t)b*HXS + n*64 + ug*8);
  const float4 h1 = *(const float4*)(hx + (size_t)b*HXS + n*64 + ug*8 + 4);
  uint4 o;
  o.x = pack2(h0.x, h0.y); o.y = pack2(h0.z, h0.w);
  o.z = pack2(h1.x, h1.y); o.w = pack2(h1.z, h1.w);
  xs0q[((size_t)n*32 + b)*8 + ug] = o;
  if (t < 32){
    int bb = t;
    const float2 g = *(const float2*)(inputs + (size_t)bb*(NN*2) + n*2);
    xi0[(((size_t)(bb>>2)*NN) + n)*4 + (bb&3)] = pack2(g.x, g.y);
  }
}

// ---------------- SpMM: one wave per (node, slice, sup); scalar meta, fixed lane offset ----------------
// 8 slices x 512B; wave-uniform edge loop (exact count, no divergence/predication).
// Slice-major grid ordering -> per-XCD working set = one 4.1MB source slab slice (L2-fit).
template<int NSUP, bool WITH_IN>
__global__ __launch_bounds__(256) void k_spmm(const int* __restrict__ row_ptr, const uint2* __restrict__ edge_s,
                                              unsigned short* xsS, uint4* xi4,
                                              int supE0, int msrc0, int mdst0,
                                              int supE1, int msrc1, int mdst1){
  constexpr int NSTATE = NSUP*16000;   // state blocks (4 waves each)
  int bid = blockIdx.x;
  if (WITH_IN && bid >= NSTATE){
    int b2 = bid - NSTATE;
    int s = b2 & 7;
    int si = (NSUP == 2) ? ((b2 >> 3) & 1) : 0;
    int chunk = (NSUP == 2) ? (b2 >> 4) : (b2 >> 3);
    int n = chunk*256 + threadIdx.x;
    if (n >= NN) return;
    int supE = si ? supE1 : supE0;
    int msrc = si ? msrc1 : msrc0;
    int mdst = si ? mdst1 : mdst0;
    size_t sb = (size_t)(msrc*8 + s)*NN, db = (size_t)(mdst*8 + s)*NN;
    int beg = row_ptr[supE*(NN+1)+n], end = row_ptr[supE*(NN+1)+n+1];
    const uint2* es = edge_s + supE*EE;
    float ai[8] = {0.f,0.f,0.f,0.f,0.f,0.f,0.f,0.f};
    for (int e = beg; e < end; ++e){
      uint2 ev = es[e];
      float v = __builtin_bit_cast(float, ev.y);
      uint4 qi = xi4[sb + ev.x];
      acc8(ai, v, qi);
    }
    uint4 oi;
    oi.x = pack2(ai[0],ai[1]); oi.y = pack2(ai[2],ai[3]); oi.z = pack2(ai[4],ai[5]); oi.w = pack2(ai[6],ai[7]);
    ntstore16(oi, &xi4[db + n]);
    return;
  }
  // ---- state wave ----
  int g = __builtin_amdgcn_readfirstlane(bid*4 + (threadIdx.x >> 6));
  int slice, si, n;
  if (NSUP == 2){
    slice = g / 16000; int r = g - slice*16000;
    si = (r >= 8000) ? 1 : 0; n = r - si*8000;
  } else {
    slice = g / 8000; si = 0; n = g - slice*8000;
  }
  int supE = si ? supE1 : supE0;
  int msrc = si ? msrc1 : msrc0;
  int mdst = si ? mdst1 : mdst0;
  int lane = threadIdx.x & 63;
  int off = slice*256 + lane*4;            // shorts: slice 512B + lane 8B
  const unsigned short* srcS = xsS + (size_t)msrc*(NN*2048);
  unsigned short* dstS = xsS + (size_t)mdst*(NN*2048);
  int beg = __builtin_amdgcn_readfirstlane(row_ptr[supE*(NN+1)+n]);
  int end = __builtin_amdgcn_readfirstlane(row_ptr[supE*(NN+1)+n+1]);
  const uint2* es = edge_s + supE*EE;

  float a0=0.f, a1=0.f, a2=0.f, a3=0.f;
  int e = beg;
  for (; e + 2 <= end; e += 2){
    uint2 ev0 = es[e], ev1 = es[e+1];
    int c0 = __builtin_amdgcn_readfirstlane((int)ev0.x);
    int c1 = __builtin_amdgcn_readfirstlane((int)ev1.x);
    float v0 = __builtin_bit_cast(float, __builtin_amdgcn_readfirstlane(ev0.y));
    float v1 = __builtin_bit_cast(float, __builtin_amdgcn_readfirstlane(ev1.y));
    const unsigned short* rp0 = srcS + (size_t)c0*2048;
    const unsigned short* rp1 = srcS + (size_t)c1*2048;
    uint2 q0 = *(const uint2*)(rp0 + off);
    uint2 q1 = *(const uint2*)(rp1 + off);
    a0 += v0*bflo(q0.x); a1 += v0*bfhi(q0.x); a2 += v0*bflo(q0.y); a3 += v0*bfhi(q0.y);
    a0 += v1*bflo(q1.x); a1 += v1*bfhi(q1.x); a2 += v1*bflo(q1.y); a3 += v1*bfhi(q1.y);
  }
  if (e < end){
    uint2 ev = es[e];
    int c = __builtin_amdgcn_readfirstlane((int)ev.x);
    float v = __builtin_bit_cast(float, __builtin_amdgcn_readfirstlane(ev.y));
    const unsigned short* rp = srcS + (size_t)c*2048;
    uint2 q = *(const uint2*)(rp + off);
    a0 += v*bflo(q.x); a1 += v*bfhi(q.x); a2 += v*bflo(q.y); a3 += v*bfhi(q.y);
  }
  uint2 o; o.x = pack2(a0, a1); o.y = pack2(a2, a3);
  ntstore8(o, (uint2*)(dstS + (size_t)n*2048 + off));
}

// ---------------- GEMM (R7 structure): 4 independent 32-row waves, A global->reg dbuf, B small LDS dbuf ----------------
template<int NCOL, bool IS_RU>
__global__ __launch_bounds__(256, 3) void k_gemm(unsigned short* xsS,                   // state slabs (slab0 = hx-bf16 / r*hx target)
                                                 const unsigned int* __restrict__ xsI,  // input dwords (8-slice layout)
                                                 const unsigned short* __restrict__ Wp, // packed [m][NCOL][64] + tail [NCOL][32]
                                                 const float* __restrict__ bias,
                                                 const float* __restrict__ hx,
                                                 float* cout,
                                                 unsigned short* ubuf){
  constexpr int CF = NCOL / 16;
  __shared__ unsigned short Bl[2][NCOL*64];
  __shared__ unsigned short Bt[NCOL*32];
  const int t = threadIdx.x;
  const int wv = t >> 6;
  const int l = t & 63;
  const int lr = l & 15;
  const int lg = l >> 4;
  const int R0 = blockIdx.x * 128;

  auto stageB = [&](int m, int buf){
    #pragma unroll
    for (int i=0;i<NCOL*8/256;i++){
      int g = t + i*256;
      int rr = g >> 3, c = g & 7;
      const unsigned short* gp = Wp + (size_t)(m*NCOL + rr)*64 + ((c ^ (rr&7)) << 3);
      stage16(gp, &Bl[buf][(size_t)(i*256 + wv*64)*8]);
    }
  };

  // per-wave A row bases (shorts; layout row-major [gemm_row][64])
  size_t abase[2];
  #pragma unroll
  for (int rf=0; rf<2; rf++)
    abase[rf] = (size_t)(R0 + wv*32 + rf*16 + lr)*64;
  auto loadA = [&](int m, uint4* dst){
    #pragma unroll
    for (int ks=0; ks<2; ks++)
      #pragma unroll
      for (int rf=0; rf<2; rf++)
        dst[ks*2+rf] = *(const uint4*)(xsS + (size_t)m*(NN*2048) + abase[rf] + ks*32 + lg*8);
  };

  // ---- prologue: A(m=0), tail frags, B0 + Btail ----
  uint4 aC[4], aN[4];
  loadA(0, aC);
  uint4 aT[2];
  #pragma unroll
  for (int rf=0; rf<2; rf++){
    int row = R0 + wv*32 + rf*16 + lr;
    int n = row >> 5, b = row & 31;
    size_t ib = (((size_t)(b>>2))*NN + n)*4 + (b&3);
    unsigned int q0=0u,q1=0u,q2=0u,q3=0u;
    if (lg == 0){
      q0 = xsI[ib];
      q1 = xsI[(size_t)8*NN*4 + ib];
      q2 = xsI[(size_t)16*NN*4 + ib];
      q3 = xsI[(size_t)24*NN*4 + ib];
    } else if (lg == 1){
      q0 = xsI[(size_t)32*NN*4 + ib];
    }
    uint4 qq; qq.x=q0; qq.y=q1; qq.z=q2; qq.w=q3;
    aT[rf] = qq;
  }
  stageB(0, 0);
  {
    #pragma unroll
    for (int i=0;i<NCOL*4/256;i++){
      int g = t + i*256;
      int rr = g >> 2, c = g & 3;
      const unsigned short* gp = Wp + (size_t)320*NCOL + rr*32 + ((c ^ (rr&3)) << 3);
      stage16(gp, &Bt[(size_t)(i*256 + wv*64)*8]);
    }
  }
  __syncthreads();

  f32x4 acc[2][CF];
  const f32x4 zero = {0.f,0.f,0.f,0.f};
  #pragma unroll
  for (int rf=0; rf<2; rf++)
    #pragma unroll
    for (int cf=0; cf<CF; cf++) acc[rf][cf] = zero;

  #pragma unroll
  for (int m=0; m<5; m++){
    int cur = m & 1;
    if (m < 4){
      stageB(m+1, cur^1);
      loadA(m+1, aN);
    }
    #pragma unroll
    for (int ks=0; ks<2; ks++){
      #pragma unroll
      for (int cf=0; cf<CF; cf++){
        int col = cf*16 + lr;
        int chunk = (ks*4 + lg) ^ (col & 7);
        bf16x8 bv = __builtin_bit_cast(bf16x8, *(const uint4*)(&Bl[cur][col*64 + chunk*8]));
        acc[0][cf] = __builtin_amdgcn_mfma_f32_16x16x32_bf16(__builtin_bit_cast(bf16x8, aC[ks*2+0]), bv, acc[0][cf], 0, 0, 0);
        acc[1][cf] = __builtin_amdgcn_mfma_f32_16x16x32_bf16(__builtin_bit_cast(bf16x8, aC[ks*2+1]), bv, acc[1][cf], 0, 0, 0);
      }
    }
    __syncthreads();
    #pragma unroll
    for (int i=0;i<4;i++) aC[i] = aN[i];
  }

  // ---- tail K-step (input features) ----
  #pragma unroll
  for (int cf=0; cf<CF; cf++){
    int col = cf*16 + lr;
    int chunk = lg ^ (col & 3);
    bf16x8 bv = __builtin_bit_cast(bf16x8, *(const uint4*)(&Bt[col*32 + chunk*8]));
    acc[0][cf] = __builtin_amdgcn_mfma_f32_16x16x32_bf16(__builtin_bit_cast(bf16x8, aT[0]), bv, acc[0][cf], 0, 0, 0);
    acc[1][cf] = __builtin_amdgcn_mfma_f32_16x16x32_bf16(__builtin_bit_cast(bf16x8, aT[1]), bv, acc[1][cf], 0, 0, 0);
  }

  // ---- epilogue (col c -> unit 4*lr+cf; vectorized stores) ----
  #pragma unroll
  for (int rf=0; rf<2; rf++){
    #pragma unroll
    for (int reg=0; reg<4; reg++){
      int row = R0 + wv*32 + rf*16 + (lg << 2) + reg;
      int n = row >> 5, b = row & 31;
      size_t rowoff = (size_t)b*HXS + (size_t)n*UU;
      size_t slot0 = (size_t)row*64;
      int o0 = lr << 2;
      if constexpr (IS_RU){
        uint2 hv = *(const uint2*)(xsS + slot0 + o0);   // hx bf16 (slab0, pre-overwrite)
        unsigned short rr4[4], uu4[4];
        #pragma unroll
        for (int cf=0; cf<4; cf++){
          int o = o0 + cf;
          float vr = acc[rf][cf][reg]   + bias[o];
          float vu = acc[rf][cf+4][reg] + bias[64+o];
          float sgr = 1.f/(1.f + __expf(-vr));
          float sgu = 1.f/(1.f + __expf(-vu));
          float h = bfu(((const unsigned short*)&hv)[cf]);
          rr4[cf] = f2bf(sgr * h);
          uu4[cf] = f2bf(sgu);
        }
        *(uint2*)(xsS + slot0 + o0) = *(uint2*)rr4;
        *(uint2*)(ubuf + rowoff + o0) = *(uint2*)uu4;
      } else {
        float4 hv = *(const float4*)(hx + rowoff + o0);
        uint2 uv = *(const uint2*)(ubuf + rowoff + o0);
        float4 ov;
        #pragma unroll
        for (int cf=0; cf<4; cf++){
          float cc = tanhf(acc[rf][cf][reg] + bias[o0+cf]);
          float uu = bfu(((const unsigned short*)&uv)[cf]);
          float h  = ((const float*)&hv)[cf];
          ((float*)&ov)[cf] = uu*h + (1.f - uu)*cc;
        }
        *(float4*)(cout + rowoff + o0) = ov;
      }
    }
  }
}

// ---------------- launcher ----------------
extern "C" void kernel_launch(void* const* d_in, const int* in_sizes, int n_in,
                              void* d_out, int out_size, void* d_ws, size_t ws_size,
                              hipStream_t stream){
  const float* inputs = (const float*)d_in[0];
  const float* hx     = (const float*)d_in[1];
  const int*   row0   = (const int*)d_in[2];
  const int*   col0   = (const int*)d_in[3];
  const float* val0   = (const float*)d_in[4];
  const int*   row1   = (const int*)d_in[5];
  const int*   col1   = (const int*)d_in[6];
  const float* val1   = (const float*)d_in[7];
  const float* W_ru   = (const float*)d_in[8];
  const float* b_ru   = (const float*)d_in[9];
  const float* W_c    = (const float*)d_in[10];
  const float* b_c    = (const float*)d_in[11];
  float* out = (float*)d_out;

  char* ws = (char*)d_ws;
  size_t off = 0;
  auto alloc = [&](size_t bytes) -> void* {
    void* p = ws + off;
    off += (bytes + 255) & ~(size_t)255;
    return p;
  };
  unsigned short* xsS   = (unsigned short*)alloc((size_t)5*NN*2048*2);  // 163.84 MB
  unsigned int*   xsI   = (unsigned int*)  alloc((size_t)5*8*NN*16);    //   5.12 MB
  unsigned short* u_buf = (unsigned short*)alloc((size_t)NB*64*2);      //  32.77 MB
  unsigned short* Wru_t = (unsigned short*)alloc((size_t)128*352*2);
  unsigned short* Wc_t  = (unsigned short*)alloc((size_t)64*352*2);
  int*   row_ptr = (int*)  alloc(2*(NN+1)*4);
  uint2* edge_s  = (uint2*)alloc((size_t)2*EE*8);
  int*   cnt     = (int*)  alloc(2*NN*4);
  int*   rp_work = (int*)  alloc(2*NN*4);
  (void)ws_size; (void)in_sizes; (void)n_in; (void)out_size;

  hipMemsetAsync(cnt, 0, 2*NN*4, stream);
  k_hist<<<(2*EE + 255)/256, 256, 0, stream>>>(row0, row1, cnt);
  k_scan<<<2, 1024, 0, stream>>>(cnt, row_ptr, rp_work);
  k_scatter<<<(2*EE + 255)/256, 256, 0, stream>>>(row0, col0, val0, row1, col1, val1, rp_work, edge_s);
  k_wpack<<<(352*192)/256, 256, 0, stream>>>(W_ru, W_c, Wru_t, Wc_t);
  k_x0<<<NN, 256, 0, stream>>>(inputs, hx, (uint4*)xsS, (unsigned int*)xsI);

  uint4* xi4 = (uint4*)xsI;

  // gconv 1: hop1 (both sups share src m0), hop2 split per support (one L2 slice window each)
  k_spmm<2, true ><<<32512, 256, 0, stream>>>(row_ptr, edge_s, xsS, xi4, 0, 0, 1, 1, 0, 3);
  k_spmm<1, true ><<<16256, 256, 0, stream>>>(row_ptr, edge_s, xsS, xi4, 0, 1, 2, 0, 1, 2);
  k_spmm<1, true ><<<16256, 256, 0, stream>>>(row_ptr, edge_s, xsS, xi4, 1, 3, 4, 1, 3, 4);
  k_gemm<128, true><<<2000, 256, 0, stream>>>(xsS, xsI, Wru_t, b_ru, hx, nullptr, u_buf);

  // gconv 2: state part = r*hx (slab 0); input diffusion reused from gconv1
  k_spmm<2, false><<<32000, 256, 0, stream>>>(row_ptr, edge_s, xsS, xi4, 0, 0, 1, 1, 0, 3);
  k_spmm<1, false><<<16000, 256, 0, stream>>>(row_ptr, edge_s, xsS, xi4, 0, 1, 2, 0, 1, 2);
  k_spmm<1, false><<<16000, 256, 0, stream>>>(row_ptr, edge_s, xsS, xi4, 1, 3, 4, 1, 3, 4);
  k_gemm<64, false><<<2000, 256, 0, stream>>>(xsS, xsI, Wc_t, b_c, hx, out, u_buf);
}